// Round 2
// 1072.120 us; speedup vs baseline: 2.1553x; 2.1553x over previous
//
#include <hip/hip_runtime.h>
#include <cstddef>

// ---------------------------------------------------------------------------
// Problem constants: B=8, S=1024, D=1024, H=16, DH=64, MAX_K=4, SCALE=8.
// Outputs: d_out = [ out (B,S,D) f32 | attn (B,H,S,S) f32 ].
// ws (bf16): Qp (B,H,S,DH) | Kp (B,H,S,DH) | Vt (B,H,DH,S) | ctx (B,S,D).
// ---------------------------------------------------------------------------

typedef __bf16 bf16x8 __attribute__((ext_vector_type(8)));
typedef __bf16 bf16x4 __attribute__((ext_vector_type(4)));
typedef float  floatx4 __attribute__((ext_vector_type(4)));

// -------------------- bf16 MFMA GEMM:  C[m,n] = sum_k A[m,k]*W[n,k] + b[n] --
// M=8192, N=1024, K=1024.  Block tile 128x128, BK=32, 4 waves (2x2 of 64x64).
// mfma_f32_16x16x32_bf16 layouts (verified):
//   A-frag: A[m=lane&15][k=(lane>>4)*8+j]   (8 contiguous k)
//   B-frag: B[k=(lane>>4)*8+j][n=lane&15] = W[n=lane&15][k]  (8 contiguous k)
//   C/D  : col=lane&15, row=(lane>>4)*4+reg
// EPI==0: bf16 to (B,H,S,DH) permuted. EPI==1: f32 row-major.
// EPI==2: bf16 to (B,H,DH,S) (transposed V), vectorized bf16x4 store.

__device__ inline bf16x4 ld_cvt4(const float* p) {
    float4 f = *(const float4*)p;
    bf16x4 v = {(__bf16)f.x, (__bf16)f.y, (__bf16)f.z, (__bf16)f.w};
    return v;
}
__device__ inline bf16x4 ld_cvt4(const __bf16* p) {
    return *(const bf16x4*)p;
}

template<int EPI, typename TA>
__global__ __launch_bounds__(256) void gemm_bt(const TA* __restrict__ A,
                                               const float* __restrict__ W,
                                               const float* __restrict__ bias,
                                               void* __restrict__ outv) {
    constexpr int K = 1024;
    __shared__ __bf16 As[128 * 40];   // rows padded 32->40 to spread banks
    __shared__ __bf16 Bs[128 * 40];

    const int tid  = threadIdx.x;
    const int lane = tid & 63;
    const int wave = tid >> 6;
    const int r = lane & 15;          // fragment row/col id
    const int t = lane >> 4;          // quad id
    const int wm = (wave >> 1) * 64;  // wave sub-tile origin (m)
    const int wn = (wave & 1) * 64;   // wave sub-tile origin (n)
    const int m0 = blockIdx.y * 128;
    const int n0 = blockIdx.x * 128;

    const int rrow = tid >> 3;        // 0..31 (staging row group)
    const int rcol = (tid & 7) * 4;   // 0..28 (staging col)

    floatx4 acc[4][4] = {};

    for (int k0 = 0; k0 < K; k0 += 32) {
        __syncthreads();
        #pragma unroll
        for (int i = 0; i < 4; i++) {
            int row = rrow + 32 * i;
            bf16x4 av = ld_cvt4(A + (size_t)(m0 + row) * K + k0 + rcol);
            *(bf16x4*)&As[row * 40 + rcol] = av;
            bf16x4 wv = ld_cvt4(W + (size_t)(n0 + row) * K + k0 + rcol);
            *(bf16x4*)&Bs[row * 40 + rcol] = wv;
        }
        __syncthreads();

        bf16x8 aF[4], bF[4];
        #pragma unroll
        for (int mi = 0; mi < 4; mi++)
            aF[mi] = *(const bf16x8*)&As[(wm + mi * 16 + r) * 40 + t * 8];
        #pragma unroll
        for (int ni = 0; ni < 4; ni++)
            bF[ni] = *(const bf16x8*)&Bs[(wn + ni * 16 + r) * 40 + t * 8];

        #pragma unroll
        for (int mi = 0; mi < 4; mi++)
            #pragma unroll
            for (int ni = 0; ni < 4; ni++)
                acc[mi][ni] = __builtin_amdgcn_mfma_f32_16x16x32_bf16(
                    aF[mi], bF[ni], acc[mi][ni], 0, 0, 0);
    }

    #pragma unroll
    for (int mi = 0; mi < 4; mi++) {
        #pragma unroll
        for (int ni = 0; ni < 4; ni++) {
            if constexpr (EPI == 2) {
                // transposed V: 4 consecutive s (= rows t*4+j) share one dh row
                int rgb = m0 + wm + mi * 16 + t * 4;      // first m (b*S+s)
                int cg  = n0 + wn + ni * 16 + r;          // n (h*DH+dh)
                int bb = rgb >> 10, s0 = rgb & 1023;
                int hh = cg >> 6,  dh = cg & 63;
                bf16x4 ov;
                #pragma unroll
                for (int j = 0; j < 4; j++)
                    ov[j] = (__bf16)(acc[mi][ni][j] + bias[cg]);
                __bf16* o = (__bf16*)outv;
                *(bf16x4*)&o[((size_t)(bb * 16 + hh) * 64 + dh) * 1024 + s0] = ov;
            } else {
                #pragma unroll
                for (int j = 0; j < 4; j++) {
                    int rg = m0 + wm + mi * 16 + t * 4 + j;   // m index (b*S+s)
                    int cg = n0 + wn + ni * 16 + r;           // n index (h*DH+dh)
                    float v = acc[mi][ni][j] + bias[cg];
                    if constexpr (EPI == 0) {
                        __bf16* o = (__bf16*)outv;
                        int bb = rg >> 10, s = rg & 1023;
                        int hh = cg >> 6,  dh = cg & 63;
                        o[((size_t)(bb * 16 + hh) * 1024 + s) * 64 + dh] = (__bf16)v;
                    } else {
                        float* o = (float*)outv;
                        o[(size_t)rg * 1024 + cg] = v;
                    }
                }
            }
        }
    }
}

// -------------------- fused attention (MFMA) -------------------------------
// Grid (S/16, H, B), 512 threads (8 waves). Per block: 16 q-rows of one (b,h).
// LDS 75.8 KiB -> 2 blocks/CU.
// Phase 1: QK^T via mfma_16x16x32_bf16; wave w owns k-strip [w*128,w*128+128).
//          K-frags loaded straight from global (L2-resident). Scores + rel-k
//          + mask penalty -> sc[16][1028] (stride 1028 f32: 16B-aligned rows,
//          <=2-way bank aliasing in all phases).
// Phase 2: row softmax: 32 threads/row, float4 scans, shfl_xor reduces.
//          rel-v bucket sums wb[9] (lo = total - hi - mid trick).
// Phase 3: attn = e*inv -> global (nontemporal f32x4, fully coalesced).
// Phase 4: AV via MFMA: 4 d-strips x 2 k-halves; upper-half waves dump
//          partials to LDS, lower-half waves reduce + rel-v epilogue -> ctx.

__global__ __launch_bounds__(512) void attn_fused(
    const __bf16* __restrict__ Qp, const __bf16* __restrict__ Kp,
    const __bf16* __restrict__ Vt, const int* __restrict__ mask,
    const float* __restrict__ pe_k, const float* __restrict__ pe_v,
    float* __restrict__ attn_out, __bf16* __restrict__ ctx) {

    constexpr int QT  = 16;
    constexpr int SCW = 1028;            // f32 row stride

    __shared__ float sc[QT][SCW];        // 65792 B  scores -> exp values
    __shared__ float pev_s[9][64];       // 2304 B
    __shared__ float rk_s[QT][9];        // rel-k row dots (pre /SCALE)
    __shared__ float wb_s[QT][9];        // rel-v bucket sums (unnormalized)
    __shared__ float inv_s[QT];
    __shared__ float pen_s[1024];        // mask penalty (0 or -1e30)
    __shared__ float pr_s[QT][66];       // phase-4 partials (upper k-half)

    const int b = blockIdx.z, h = blockIdx.y;
    const int q0 = blockIdx.x * QT;
    const int tid = threadIdx.x;
    const int lane = tid & 63;
    const int w  = tid >> 6;             // wave 0..7
    const int lr = lane & 15;
    const int lg = lane >> 4;
    const size_t head = (size_t)(b * 16 + h) << 16;   // * S * DH

    for (int i = tid; i < 1024; i += 512)
        pen_s[i] = mask[b * 1024 + i] ? 0.f : -1e30f;
    for (int i = tid; i < 576; i += 512)
        (&pev_s[0][0])[i] = pe_v[i];

    // rel-k: rk[q][j] = (Q[q] . pe_k[j]) / SCALE   (144 threads)
    if (tid < 144) {
        int q = tid / 9, j = tid - q * 9;
        const __bf16* qrow = Qp + head + (size_t)(q0 + q) * 64;
        const float* pk = pe_k + j * 64;
        float a = 0.f;
        #pragma unroll
        for (int d = 0; d < 64; d++) a += (float)qrow[d] * pk[d];
        rk_s[q][j] = a * 0.125f;
    }

    // Q fragments (identical in every wave; 2 KB, L1/L2-resident)
    bf16x8 qF[2];
    #pragma unroll
    for (int ks = 0; ks < 2; ks++)
        qF[ks] = *(const bf16x8*)(Qp + head +
            (size_t)(q0 + lr) * 64 + ks * 32 + lg * 8);

    __syncthreads();

    // ---------------- phase 1: QK^T + rel-k + mask -> sc -------------------
    {
        const int kbase = w * 128;
        #pragma unroll 4
        for (int kk = 0; kk < 8; kk++) {
            const int kg = kbase + kk * 16 + lr;         // this lane's k col
            const __bf16* krow = Kp + head + (size_t)kg * 64 + lg * 8;
            bf16x8 kf0 = *(const bf16x8*)krow;
            bf16x8 kf1 = *(const bf16x8*)(krow + 32);
            float pen = pen_s[kg];
            floatx4 acc = {};
            acc = __builtin_amdgcn_mfma_f32_16x16x32_bf16(qF[0], kf0, acc, 0, 0, 0);
            acc = __builtin_amdgcn_mfma_f32_16x16x32_bf16(qF[1], kf1, acc, 0, 0, 0);
            #pragma unroll
            for (int j = 0; j < 4; j++) {
                int ql = lg * 4 + j;
                int dk = kg - (q0 + ql);
                dk = min(max(dk, -4), 4);
                sc[ql][kg] = fmaf(acc[j], 0.125f, rk_s[ql][dk + 4]) + pen;
            }
        }
    }
    __syncthreads();

    // ---------------- phase 2: softmax (32 threads per row) ----------------
    {
        const int row = tid >> 5;
        const int cc  = tid & 31;
        const int qg  = q0 + row;

        float mx = -1e30f;
        #pragma unroll
        for (int i = 0; i < 8; i++) {
            floatx4 v = *(const floatx4*)&sc[row][(cc + 32 * i) * 4];
            mx = fmaxf(mx, fmaxf(fmaxf(v[0], v[1]), fmaxf(v[2], v[3])));
        }
        #pragma unroll
        for (int off = 16; off >= 1; off >>= 1) mx = fmaxf(mx, __shfl_xor(mx, off));

        float ssum = 0.f, shi = 0.f;
        const int thr_hi = qg + 4;
        #pragma unroll
        for (int i = 0; i < 8; i++) {
            int k4 = (cc + 32 * i) * 4;
            floatx4 v = *(const floatx4*)&sc[row][k4];
            floatx4 e;
            e[0] = __expf(v[0] - mx); e[1] = __expf(v[1] - mx);
            e[2] = __expf(v[2] - mx); e[3] = __expf(v[3] - mx);
            *(floatx4*)&sc[row][k4] = e;
            ssum += (e[0] + e[1]) + (e[2] + e[3]);
            shi  += (k4 + 0 >= thr_hi ? e[0] : 0.f) + (k4 + 1 >= thr_hi ? e[1] : 0.f)
                  + (k4 + 2 >= thr_hi ? e[2] : 0.f) + (k4 + 3 >= thr_hi ? e[3] : 0.f);
        }
        #pragma unroll
        for (int off = 16; off >= 1; off >>= 1) {
            ssum += __shfl_xor(ssum, off);
            shi  += __shfl_xor(shi, off);
        }

        // middle buckets (k = qg-3 .. qg+3), then lo = total - hi - mid
        if (cc >= 1 && cc <= 7) {
            int kmid = qg + (cc - 4);
            wb_s[row][cc] = ((unsigned)kmid < 1024u) ? sc[row][kmid] : 0.f;
        }
        if (cc == 0) {
            float msum = 0.f;
            #pragma unroll
            for (int jj = 1; jj <= 7; jj++) msum += wb_s[row][jj];
            wb_s[row][0] = ssum - shi - msum;
            wb_s[row][8] = shi;
            inv_s[row]   = 1.f / ssum;
        }
    }
    __syncthreads();

    // ---------------- phase 3: attn = e * inv -> global (nontemporal) ------
    {
        float* abase = attn_out + ((size_t)(b * 16 + h) * 1024 + q0) * 1024;
        #pragma unroll 4
        for (int it = 0; it < 8; it++) {
            int idx = it * 512 + tid;
            int rr = idx >> 8, c4 = idx & 255;
            floatx4 v = *(const floatx4*)&sc[rr][c4 * 4];
            float iv = inv_s[rr];
            floatx4 o = v * iv;
            __builtin_nontemporal_store(o, (floatx4*)(abase + (size_t)rr * 1024 + c4 * 4));
        }
    }

    // ---------------- phase 4: AV (MFMA, 4 d-strips x 2 k-halves) ----------
    {
        const int d0 = (w & 3) * 16;           // d sub-tile
        const int kh = w >> 2;                 // k half 0..1
        const float* srow = &sc[lr][lg * 8];
        const __bf16* vbase = Vt + head + (size_t)(d0 + lr) * 1024 + lg * 8;

        floatx4 acc = {};
        const int kend = kh * 512 + 512;
        #pragma unroll 4
        for (int k0 = kh * 512; k0 < kend; k0 += 32) {
            floatx4 e0 = *(const floatx4*)&srow[k0];
            floatx4 e1 = *(const floatx4*)&srow[k0 + 4];
            bf16x8 aF = {(__bf16)e0[0], (__bf16)e0[1], (__bf16)e0[2], (__bf16)e0[3],
                         (__bf16)e1[0], (__bf16)e1[1], (__bf16)e1[2], (__bf16)e1[3]};
            bf16x8 bF = *(const bf16x8*)(vbase + k0);
            acc = __builtin_amdgcn_mfma_f32_16x16x32_bf16(aF, bF, acc, 0, 0, 0);
        }

        if (kh == 1) {
            #pragma unroll
            for (int j = 0; j < 4; j++)
                pr_s[lg * 4 + j][d0 + lr] = acc[j];
        }
        __syncthreads();
        if (kh == 0) {
            const int dg = d0 + lr;
            #pragma unroll
            for (int j = 0; j < 4; j++) {
                int ql = lg * 4 + j;
                float relv = 0.f;
                #pragma unroll
                for (int jj = 0; jj < 9; jj++) relv += wb_s[ql][jj] * pev_s[jj][dg];
                float val = (acc[j] + pr_s[ql][dg] + relv) * inv_s[ql];
                ctx[((size_t)(b * 1024 + q0 + ql)) * 1024 + h * 64 + dg] = (__bf16)val;
            }
        }
    }
}

// ---------------------------------------------------------------------------
extern "C" void kernel_launch(void* const* d_in, const int* in_sizes, int n_in,
                              void* d_out, int out_size, void* d_ws, size_t ws_size,
                              hipStream_t stream) {
    const float* query = (const float*)d_in[0];
    const float* key   = (const float*)d_in[1];
    const float* value = (const float*)d_in[2];
    const int*   mask  = (const int*)d_in[3];
    const float* Wq = (const float*)d_in[4];
    const float* bq = (const float*)d_in[5];
    const float* Wk = (const float*)d_in[6];
    const float* bk = (const float*)d_in[7];
    const float* Wv = (const float*)d_in[8];
    const float* bv = (const float*)d_in[9];
    const float* Wo = (const float*)d_in[10];
    const float* bo = (const float*)d_in[11];
    const float* pe_k = (const float*)d_in[12];
    const float* pe_v = (const float*)d_in[13];

    __bf16* Qp  = (__bf16*)d_ws;          // (B,H,S,DH) bf16
    __bf16* Kp  = Qp + 8388608;           // (B,H,S,DH) bf16
    __bf16* Vt  = Kp + 8388608;           // (B,H,DH,S) bf16 (transposed V)
    __bf16* ctx = Vt + 8388608;           // (B,S,D) bf16
    float* outp  = (float*)d_out;         // (B,S,D) f32
    float* attnp = outp + 8388608;        // (B,H,S,S) f32

    dim3 gg(8, 64, 1);                    // N/128 x M/128
    gemm_bt<0, float><<<gg, 256, 0, stream>>>(query, Wq, bq, Qp);
    gemm_bt<0, float><<<gg, 256, 0, stream>>>(key,   Wk, bk, Kp);
    gemm_bt<2, float><<<gg, 256, 0, stream>>>(value, Wv, bv, Vt);
    attn_fused<<<dim3(64, 16, 8), 512, 0, stream>>>(Qp, Kp, Vt, mask,
                                                    pe_k, pe_v, attnp, ctx);
    gemm_bt<1, __bf16><<<gg, 256, 0, stream>>>(ctx, Wo, bo, outp);
}